// Round 7
// baseline (263.923 us; speedup 1.0000x reference)
//
#include <hip/hip_runtime.h>

#define NPTS  32768
#define DIM   256
#define KCB   1024

#define ZQ_OFF   0
#define LOSS_OFF 8388608
#define IDX_OFF  8388609

typedef __attribute__((ext_vector_type(8))) short short8;
typedef __attribute__((ext_vector_type(4))) float f32x4;

// z layout [B, D, H, W]: point n = b*1024 + h*32 + w ; elem (n,d) at b*262144 + d*1024 + hw
__device__ __forceinline__ int z_base(int n) { return ((n >> 10) << 18) | (n & 1023); }

// RNE float->bf16 (bits)
__device__ __forceinline__ unsigned short f2bf(float f) {
    unsigned u = __float_as_uint(f);
    u += 0x7FFFu + ((u >> 16) & 1u);
    return (unsigned short)(u >> 16);
}

__device__ __forceinline__ unsigned long long pack_vi(float v, int i) {
    unsigned int u = __float_as_uint(v);
    unsigned int key = (u & 0x80000000u) ? ~u : u;   // monotone float->uint (finite)
    return ((unsigned long long)key << 32) | (unsigned int)i;
}

// ---- numpy pairwise sum (AVX512 npyv order) of squares, 128 elems ----
__device__ __forceinline__ float np_half_sq(const float* __restrict__ p, int stride) {
    float S[16];
#pragma unroll
    for (int l = 0; l < 16; ++l) {
        float t[8];
#pragma unroll
        for (int j = 0; j < 8; ++j) {
            float v = p[(j * 16 + l) * stride];
            t[j] = __fmul_rn(v, v);
        }
        S[l] = __fadd_rn(__fadd_rn(__fadd_rn(t[0], t[1]), __fadd_rn(t[2], t[3])),
                         __fadd_rn(__fadd_rn(t[4], t[5]), __fadd_rn(t[6], t[7])));
    }
    float u[8];
#pragma unroll
    for (int i = 0; i < 8; ++i) u[i] = __fadd_rn(S[i], S[i + 8]);
    float v4[4];
#pragma unroll
    for (int i = 0; i < 4; ++i) v4[i] = __fadd_rn(u[i], u[i + 4]);
    return __fadd_rn(__fadd_rn(v4[0], v4[2]), __fadd_rn(v4[1], v4[3]));
}
// same, also accumulating sum of |v| (order-free, used only for eps bound)
__device__ __forceinline__ float np_half_sq_abs(const float* __restrict__ p, int stride,
                                                float* asum) {
    float S[16]; float a = *asum;
#pragma unroll
    for (int l = 0; l < 16; ++l) {
        float t[8];
#pragma unroll
        for (int j = 0; j < 8; ++j) {
            float v = p[(j * 16 + l) * stride];
            t[j] = __fmul_rn(v, v);
            a += fabsf(v);
        }
        S[l] = __fadd_rn(__fadd_rn(__fadd_rn(t[0], t[1]), __fadd_rn(t[2], t[3])),
                         __fadd_rn(__fadd_rn(t[4], t[5]), __fadd_rn(t[6], t[7])));
    }
    float u[8];
#pragma unroll
    for (int i = 0; i < 8; ++i) u[i] = __fadd_rn(S[i], S[i + 8]);
    float v4[4];
#pragma unroll
    for (int i = 0; i < 4; ++i) v4[i] = __fadd_rn(u[i], u[i + 4]);
    *asum = a;
    return __fadd_rn(__fadd_rn(v4[0], v4[2]), __fadd_rn(v4[1], v4[3]));
}
__device__ __forceinline__ float np_sum256_sq(const float* __restrict__ p, int stride) {
    return __fadd_rn(np_half_sq(p, stride), np_half_sq(p + 128 * stride, stride));
}

// blocks 0..127: z2 + eps (single read). blocks 128..131: ebf16 convert + e2/e2h.
__global__ __launch_bounds__(256) void setup_kernel(
    const float* __restrict__ z, const float* __restrict__ emb,
    float* __restrict__ z2, float* __restrict__ eps,
    float* __restrict__ e2, float* __restrict__ e2h,
    unsigned short* __restrict__ ebf,
    double* __restrict__ loss_acc, unsigned int* __restrict__ ticket)
{
    if (blockIdx.x < 128) {
        int n = blockIdx.x * 256 + threadIdx.x;
        const float* p = z + z_base(n);
        float a = 0.0f;
        float h0 = np_half_sq_abs(p, 1024, &a);
        float h1 = np_half_sq_abs(p + 128 * 1024, 1024, &a);
        z2[n] = __fadd_rn(h0, h1);
        // |d~-d| <= 2 * (2^-18 * sum|z|) + combine slack  (bf16 RNE both operands,
        // |e|<=2^-10; factor 2 for two-sided threshold argument)
        eps[n] = __builtin_fmaf(1e-5f, a, 3e-4f);
        if (blockIdx.x == 0 && threadIdx.x == 0) { *loss_acc = 0.0; *ticket = 0u; }
    } else {
        int kb = (blockIdx.x - 128) * 256;
        const float2* s2 = (const float2*)(emb + kb * 256);
        unsigned int* d2 = (unsigned int*)(ebf + kb * 256);
        for (int i = threadIdx.x; i < 256 * 128; i += 256) {
            float2 v = s2[i];
            d2[i] = (unsigned)f2bf(v.x) | ((unsigned)f2bf(v.y) << 16);
        }
        int k = kb + threadIdx.x;
        float s = np_sum256_sq(emb + k * DIM, 1);
        e2[k] = s;
        e2h[k] = 0.5f * s;
    }
}

// ---------------- fused: MFMA filter -> exact recheck -> idx + zq + loss ----------------
// block = 64 points; 4 waves, each wave owns all 64 pts x its k-quarter (256 k).
// Barrier-free main loop: B-frags straight from global (L2) into VGPRs, A-frags
// from persistent zs LDS tile; per-point thresholds in registers via shfl_xor.
#define ZS_STRIDE 264
#define CL_SLOTS  48

__global__ __launch_bounds__(256) void dist_fused_kernel(
    const float* __restrict__ z, const float* __restrict__ emb,
    const unsigned short* __restrict__ ebf,
    const float* __restrict__ z2w, const float* __restrict__ e2w,
    const float* __restrict__ e2hw, const float* __restrict__ epsw,
    float* __restrict__ out_idx, float* __restrict__ zq,
    double* __restrict__ loss_acc, unsigned int* __restrict__ ticket,
    float* __restrict__ out_loss)
{
    __shared__ __align__(16) short zs[64 * ZS_STRIDE];   // bf16 z tile; later reused as zx f32
    __shared__ int clS[64 * CL_SLOTS];
    __shared__ unsigned int cntS[64];
    __shared__ unsigned long long bestS[64];
    __shared__ float z2S[64];
    __shared__ double sredL[4];
    __shared__ int ovfS;

    const int tid = threadIdx.x;
    const int w   = tid >> 6;
    const int l   = tid & 63;
    const int n16 = l & 15;
    const int q   = l >> 4;
    const int n0  = blockIdx.x << 6;
    const int zb  = z_base(n0);
    const int kq  = w << 8;                  // wave's k-quarter base

    if (tid < 64) {
        cntS[tid] = 0u;
        bestS[tid] = 0x7FFFFFFFFFFFFFFFULL;
        z2S[tid] = z2w[n0 + tid];
    }
    if (tid == 0) ovfS = 0;

    // stage zs: fp32 -> bf16, transpose to [pt][d]
    {
        int qq = tid & 15, d0 = tid >> 4;
#pragma unroll 4
        for (int i = 0; i < 16; ++i) {
            int d = d0 + 16 * i;
            float4 v = *(const float4*)(z + zb + (d << 10) + 4 * qq);
            zs[(4 * qq + 0) * ZS_STRIDE + d] = (short)f2bf(v.x);
            zs[(4 * qq + 1) * ZS_STRIDE + d] = (short)f2bf(v.y);
            zs[(4 * qq + 2) * ZS_STRIDE + d] = (short)f2bf(v.z);
            zs[(4 * qq + 3) * ZS_STRIDE + d] = (short)f2bf(v.w);
        }
    }

    float epsr[4][4];                        // eps for C rows pt = mt*16 + q*4 + r
#pragma unroll
    for (int mt = 0; mt < 4; ++mt)
#pragma unroll
        for (int r = 0; r < 4; ++r)
            epsr[mt][r] = epsw[n0 + mt * 16 + q * 4 + r];

    __syncthreads();

    f32x4 acc[4][4];
    float Mx[4][4];
#pragma unroll
    for (int mt = 0; mt < 4; ++mt)
#pragma unroll
        for (int nt = 0; nt < 4; ++nt) acc[mt][nt] = (f32x4)0.0f;
#pragma unroll
    for (int mt = 0; mt < 4; ++mt)
#pragma unroll
        for (int r = 0; r < 4; ++r) Mx[mt][r] = -3.4e38f;

    // B fragment loads: lane n16 -> codeword row, quad -> d-offset; dwordx4 each.
    int4 bcur[4];
#pragma unroll
    for (int nt = 0; nt < 4; ++nt)
        bcur[nt] = *(const int4*)(ebf + ((kq + nt * 16 + n16) << 8) + q * 8);

#pragma unroll 1
    for (int step = 0; step < 32; ++step) {          // 4 subtiles (64 k) x 8 d-chunks
        const int s = step >> 3, dc = step & 7;
        short8 af[4];
#pragma unroll
        for (int mt = 0; mt < 4; ++mt)
            af[mt] = *(const short8*)(zs + (mt * 16 + n16) * ZS_STRIDE + dc * 32 + q * 8);
#pragma unroll
        for (int nt = 0; nt < 4; ++nt) {
            short8 bf = *(short8*)&bcur[nt];
#pragma unroll
            for (int mt = 0; mt < 4; ++mt)
                acc[mt][nt] = __builtin_amdgcn_mfma_f32_16x16x32_bf16(af[mt], bf, acc[mt][nt], 0, 0, 0);
        }
        if (step < 31) {                             // load B for next step (WAR on bcur)
            const int sn = (step + 1) >> 3, dcn = (step + 1) & 7;
#pragma unroll
            for (int nt = 0; nt < 4; ++nt)
                bcur[nt] = *(const int4*)(ebf + ((kq + sn * 64 + nt * 16 + n16) << 8) + dcn * 32 + q * 8);
        }
        if (dc == 7) {                               // subtile epilogue, register-only
            float e2hr[4]; int kg[4];
#pragma unroll
            for (int nt = 0; nt < 4; ++nt) {
                kg[nt] = kq + s * 64 + nt * 16 + n16;
                e2hr[nt] = e2hw[kg[nt]];
            }
#pragma unroll
            for (int mt = 0; mt < 4; ++mt)
#pragma unroll
                for (int nt = 0; nt < 4; ++nt)
#pragma unroll
                    for (int r = 0; r < 4; ++r)
                        acc[mt][nt][r] -= e2hr[nt];  // s~ = dot - e2/2, in place
#pragma unroll
            for (int mt = 0; mt < 4; ++mt)
#pragma unroll
                for (int r = 0; r < 4; ++r) {
                    float m = fmaxf(fmaxf(acc[mt][0][r], acc[mt][1][r]),
                                    fmaxf(acc[mt][2][r], acc[mt][3][r]));
                    m = fmaxf(m, __shfl_xor(m, 1, 64));
                    m = fmaxf(m, __shfl_xor(m, 2, 64));
                    m = fmaxf(m, __shfl_xor(m, 4, 64));
                    m = fmaxf(m, __shfl_xor(m, 8, 64));
                    Mx[mt][r] = fmaxf(Mx[mt][r], m); // update max BEFORE recording -> no redo
                }
#pragma unroll
            for (int mt = 0; mt < 4; ++mt)
#pragma unroll
                for (int r = 0; r < 4; ++r) {
                    const float th = Mx[mt][r] - epsr[mt][r];
                    const int row = mt * 16 + q * 4 + r;
#pragma unroll
                    for (int nt = 0; nt < 4; ++nt) {
                        if (acc[mt][nt][r] >= th) {
                            unsigned int p = atomicAdd(&cntS[row], 1u);
                            if (p < CL_SLOTS) clS[row * CL_SLOTS + p] = kg[nt];
                            else ovfS = 1;
                        }
                    }
                }
#pragma unroll
            for (int mt = 0; mt < 4; ++mt)
#pragma unroll
                for (int nt = 0; nt < 4; ++nt) acc[mt][nt] = (f32x4)0.0f;
        }
    }

    // ---------------- exact recheck (bit-identical fp32 chain) ----------------
    __syncthreads();
    float* zx = (float*)zs;                  // [32 dd][68] fp32 chunk, reuse zs
    const int pt = tid & 63;
    const int s0 = tid >> 6;                 // 4 slot-threads per point
    unsigned int nc = cntS[pt]; if (nc > CL_SLOTS) nc = CL_SLOTS;
    bool  act[12]; int kE[12]; float accE[12];
#pragma unroll
    for (int j = 0; j < 12; ++j) {
        unsigned int s = (unsigned int)s0 + 4u * j;
        act[j] = s < nc;
        kE[j] = act[j] ? clS[pt * CL_SLOTS + s] : 0;
        accE[j] = 0.0f;
    }
#pragma unroll 1
    for (int dt = 0; dt < 8; ++dt) {
        const int dbase = dt * 32;
        __syncthreads();
        {
            int qq = tid & 15, dd0 = tid >> 4;
            float4 v0 = *(const float4*)(z + zb + ((dbase + dd0) << 10) + 4 * qq);
            float4 v1 = *(const float4*)(z + zb + ((dbase + dd0 + 16) << 10) + 4 * qq);
            *(float4*)(zx + dd0 * 68 + 4 * qq) = v0;
            *(float4*)(zx + (dd0 + 16) * 68 + 4 * qq) = v1;
        }
        __syncthreads();
#pragma unroll
        for (int j = 0; j < 12; ++j) {
            if (!act[j]) continue;
            const float* er = emb + kE[j] * 256 + dbase;
            float ev[32];
#pragma unroll
            for (int c = 0; c < 8; ++c) *(float4*)(ev + 4 * c) = *(const float4*)(er + 4 * c);
            float a = accE[j];
#pragma unroll
            for (int dd = 0; dd < 32; ++dd)
                a = __builtin_fmaf(zx[dd * 68 + pt], ev[dd], a);
            accE[j] = a;
        }
    }
#pragma unroll
    for (int j = 0; j < 12; ++j) {
        if (!act[j]) continue;
        int k = kE[j];
        float t1 = __fadd_rn(z2S[pt], e2w[k]);
        float d  = __fsub_rn(t1, __fmul_rn(2.0f, accE[j]));
        atomicMin(&bestS[pt], pack_vi(d, k));   // lexicographic (d, k): np argmin semantics
    }
    __syncthreads();

    if (ovfS) {   // near-impossible fallback: full exact scan for overflowed points
        for (int row = 0; row < 64; ++row) {
            if (cntS[row] <= (unsigned)CL_SLOTS) continue;
            float fa[4] = {0.f, 0.f, 0.f, 0.f};
            for (int dt = 0; dt < 8; ++dt) {
                const int dbase = dt * 32;
                __syncthreads();
                {
                    int qq = tid & 15, dd0 = tid >> 4;
                    float4 v0 = *(const float4*)(z + zb + ((dbase + dd0) << 10) + 4 * qq);
                    float4 v1 = *(const float4*)(z + zb + ((dbase + dd0 + 16) << 10) + 4 * qq);
                    *(float4*)(zx + dd0 * 68 + 4 * qq) = v0;
                    *(float4*)(zx + (dd0 + 16) * 68 + 4 * qq) = v1;
                }
                __syncthreads();
                for (int c = 0; c < 4; ++c) {
                    const float* er = emb + (tid + 256 * c) * 256 + dbase;
                    for (int dd = 0; dd < 32; ++dd)
                        fa[c] = __builtin_fmaf(zx[dd * 68 + row], er[dd], fa[c]);
                }
            }
            for (int c = 0; c < 4; ++c) {
                int k = tid + 256 * c;
                float t1 = __fadd_rn(z2S[row], e2w[k]);
                float d  = __fsub_rn(t1, __fmul_rn(2.0f, fa[c]));
                atomicMin(&bestS[row], pack_vi(d, k));
            }
            __syncthreads();
        }
    }
    __syncthreads();

    if (tid < 64)
        out_idx[n0 + tid] = (float)(unsigned int)(bestS[tid] & 0xFFFFFFFFULL);

    // ---------------- fused zq write + loss partial ----------------
    {
        const int ptz = tid & 63;
        const int dg  = tid >> 6;            // d-range [dg*64, dg*64+64)
        const int kb  = (int)(unsigned int)(bestS[ptz] & 0xFFFFFFFFULL);
        const float* er = emb + (kb << 8) + (dg << 6);
        const float* zp = z  + zb + ((dg << 6) << 10) + ptz;
        float*       qp = zq + zb + ((dg << 6) << 10) + ptz;
        double sl = 0.0;
#pragma unroll 8
        for (int dd = 0; dd < 64; ++dd) {
            float ev = er[dd];
            float zv = zp[dd << 10];
            qp[dd << 10] = ev;
            float df = ev - zv;
            sl = fma((double)df, (double)df, sl);
        }
        for (int off = 32; off; off >>= 1) sl += __shfl_down(sl, off, 64);
        if (l == 0) sredL[w] = sl;
    }
    __syncthreads();
    if (tid == 0) {
        double t = (sredL[0] + sredL[1]) + (sredL[2] + sredL[3]);
        atomicAdd(loss_acc, t);
        __threadfence();
        unsigned int old = atomicAdd(ticket, 1u);
        if (old == gridDim.x - 1) {
            double total = atomicAdd(loss_acc, 0.0);   // coherent read
            out_loss[0] = (float)(1.25 * (total / 8388608.0));
        }
    }
}

extern "C" void kernel_launch(void* const* d_in, const int* in_sizes, int n_in,
                              void* d_out, int out_size, void* d_ws, size_t ws_size,
                              hipStream_t stream) {
    const float* z   = (const float*)d_in[0];
    const float* emb = (const float*)d_in[1];
    float* out = (float*)d_out;

    // ws: z2[32768]f32 @0 | eps[32768]f32 @131072 | e2[1024] @262144 |
    //     e2h[1024] @266240 | ebf16[262144]u16 @270336 | loss f64 @794624 | ticket @794632
    float* z2w = (float*)d_ws;
    float* epsw = (float*)((char*)d_ws + 131072);
    float* e2w = (float*)((char*)d_ws + 262144);
    float* e2hw = (float*)((char*)d_ws + 266240);
    unsigned short* ebf = (unsigned short*)((char*)d_ws + 270336);
    double* loss_acc = (double*)((char*)d_ws + 794624);
    unsigned int* ticket = (unsigned int*)((char*)d_ws + 794632);

    setup_kernel<<<132, 256, 0, stream>>>(z, emb, z2w, epsw, e2w, e2hw, ebf,
                                          loss_acc, ticket);
    dist_fused_kernel<<<NPTS / 64, 256, 0, stream>>>(z, emb, ebf, z2w, e2w, e2hw, epsw,
                                                     out + IDX_OFF, out + ZQ_OFF,
                                                     loss_acc, ticket, out + LOSS_OFF);
}